// Round 3
// baseline (348.881 us; speedup 1.0000x reference)
//
#include <hip/hip_runtime.h>
#include <math.h>

#define EPSF 1e-8f
#define Bn 2
#define Tn 512
#define Dn 64
#define Ln 4
#define ROWS (Bn*Tn)
#define NELEM (Bn*Tn*Dn)

__device__ __forceinline__ float sigmoidf_(float x){ return 1.0f/(1.0f+expf(-x)); }
__device__ __forceinline__ float softplusf_(float x){ return fmaxf(x,0.0f) + log1pf(expf(-fabsf(x))); }

__device__ __forceinline__ float waveReduceSum(float v){
  #pragma unroll
  for (int off=1; off<64; off<<=1) v += __shfl_xor(v, off, 64);
  return v;
}
__device__ __forceinline__ float waveReduceMax(float v){
  #pragma unroll
  for (int off=1; off<64; off<<=1) v = fmaxf(v, __shfl_xor(v, off, 64));
  return v;
}

// ---- prologue: pnorm(basin_seq) -> sA (blocks 0..255, 4 rows each) ; temps (block 256)
__global__ __launch_bounds__(256) void k_prologue(
    const float* __restrict__ basin_seq, float* __restrict__ sA,
    const float* __restrict__ W_temp, const float* __restrict__ b_temp,
    const float* __restrict__ cb0, float* __restrict__ temps){
  int tid = threadIdx.x, wid = tid>>6, lane = tid&63;
  if (blockIdx.x < 256){
    int row = blockIdx.x*4 + wid;
    float s = softplusf_(basin_seq[row*Dn+lane]);
    float sum = waveReduceSum(s);
    float p = fmaxf(s/(sum+EPSF), EPSF);
    float sum2 = waveReduceSum(p);
    sA[row*Dn+lane] = sqrtf(p/(sum2+EPSF));
  } else if (tid < 64){
    float cbv = cb0[tid];
    #pragma unroll
    for (int l=0;l<Ln;l++){
      float v = waveReduceSum(W_temp[l*Dn + tid]*cbv);
      if (tid==0) temps[l] = sigmoidf_(v + b_temp[l]) + 0.5f;
    }
  }
}

// ---- QFI attention; one row per 512-thread block, 4 blocks/CU -> full occupancy.
// MODE 0: pass0 l<3  : write xout(=st[l]) + pnorm -> sbuf_out
// MODE 1: pass0 l==3 : write xout(=st[3])
// MODE 2: pass1 l<3  : fbgate(l+1) + write xout + pnorm -> sbuf_out
// MODE 3: pass1 l==3 : final residual -> xout(=out)
template<int MODE>
__global__ __launch_bounds__(512, 8) void k_attn(
    const float* __restrict__ xin, const float* __restrict__ sbuf,
    const float* __restrict__ temps, const float* __restrict__ res_scale, int l,
    float* __restrict__ xout, float* __restrict__ sbuf_out,
    const float* __restrict__ Wfb_next, const float* __restrict__ bfb_next,
    const float* __restrict__ prev_next,
    const float* __restrict__ basin_seq, const float* __restrict__ rsg){
  int row = blockIdx.x;       // b*T + i
  int b = row >> 9;           // T = 512
  int tid = threadIdx.x, wid = tid>>6, lane = tid&63;
  __shared__ __align__(16) float s_i[64];
  __shared__ float lg[512];
  __shared__ float red[512];
  __shared__ float redw[16];
  __shared__ __align__(16) float comb[128];
  if (tid < 64) s_i[tid] = sbuf[row*Dn + tid];
  __syncthreads();
  float invT = 1.0f / fmaxf(temps[l], 1e-6f);
  // --- loop 1: one inner product per thread (j = tid)
  const float4* sj  = (const float4*)(sbuf + (size_t)b*Tn*Dn + (size_t)tid*Dn);
  const float4* si4 = (const float4*)s_i;
  float a0=0.f, a1=0.f;
  #pragma unroll
  for (int k=0;k<16;k+=2){
    float4 x0=si4[k],   y0=sj[k];
    float4 x1=si4[k+1], y1=sj[k+1];
    a0 += x0.x*y0.x + x0.y*y0.y + x0.z*y0.z + x0.w*y0.w;
    a1 += x1.x*y1.x + x1.y*y1.y + x1.z*y1.z + x1.w*y1.w;
  }
  float inner = fminf(fmaxf(a0+a1, -1.0f+1e-6f), 1.0f-1e-6f);
  float logit = -2.0f*acosf(inner)*invT;
  // --- softmax (wave shuffle + 8-way LDS)
  float lmax = waveReduceMax(logit);
  if (lane==0) redw[wid] = lmax;
  __syncthreads();
  float maxv = redw[0];
  #pragma unroll
  for (int w=1;w<8;w++) maxv = fmaxf(maxv, redw[w]);
  float e = expf(logit - maxv);
  lg[tid] = e;
  float lsum = waveReduceSum(e);
  if (lane==0) redw[8+wid] = lsum;
  __syncthreads();
  float invSum = redw[8];
  #pragma unroll
  for (int w=1;w<8;w++) invSum += redw[8+w];
  invSum = 1.0f/invSum;
  // --- PV: wave w handles j in [w*64, w*64+64), 64 lanes cover d
  const float* xb  = xin + (size_t)b*Tn*Dn + (size_t)(wid*64)*Dn + lane;
  const float* lgp = lg + wid*64;
  float p0=0.f,p1=0.f,p2=0.f,p3=0.f;
  #pragma unroll 4
  for (int j=0;j<64;j+=4){
    p0 += lgp[j]  *xb[(size_t)j*Dn];
    p1 += lgp[j+1]*xb[(size_t)(j+1)*Dn];
    p2 += lgp[j+2]*xb[(size_t)(j+2)*Dn];
    p3 += lgp[j+3]*xb[(size_t)(j+3)*Dn];
  }
  red[tid] = (p0+p1)+(p2+p3);
  __syncthreads();
  float o = 0.f;
  if (tid < 64){
    float attn = 0.f;
    #pragma unroll
    for (int w=0;w<8;w++) attn += red[w*64+tid];
    attn *= invSum;
    float xi = xin[row*Dn + tid];
    float rs = res_scale[l];
    o = xi + rs*(attn - xi);
  }
  if constexpr (MODE == 0){
    if (tid < 64){
      xout[row*Dn+tid] = o;
      float s = softplusf_(o);
      float sum = waveReduceSum(s);
      float p = fmaxf(s/(sum+EPSF), EPSF);
      float sum2 = waveReduceSum(p);
      sbuf_out[row*Dn+tid] = sqrtf(p/(sum2+EPSF));
    }
  } else if constexpr (MODE == 1){
    if (tid < 64) xout[row*Dn+tid] = o;
  } else if constexpr (MODE == 2){
    if (tid < 64){ comb[tid] = o; comb[64+tid] = prev_next[row*Dn+tid]; }
    __syncthreads();
    if (tid < 64){
      const float4* W  = (const float4*)(Wfb_next + (size_t)tid*2*Dn);
      const float4* c4 = (const float4*)comb;
      float g0=0.f,g1=0.f;
      #pragma unroll
      for (int k=0;k<32;k+=2){
        float4 w0=W[k],   c0=c4[k];
        float4 w1=W[k+1], c1=c4[k+1];
        g0 += w0.x*c0.x + w0.y*c0.y + w0.z*c0.z + w0.w*c0.w;
        g1 += w1.x*c1.x + w1.y*c1.y + w1.z*c1.z + w1.w*c1.w;
      }
      float g = sigmoidf_(g0+g1 + bfb_next[tid]);
      float pvv = comb[64+tid];
      float xg = o*g + pvv*(1.0f-g);
      xout[row*Dn+tid] = xg;
      float s = softplusf_(xg);
      float sum = waveReduceSum(s);
      float p = fmaxf(s/(sum+EPSF), EPSF);
      float sum2 = waveReduceSum(p);
      sbuf_out[row*Dn+tid] = sqrtf(p/(sum2+EPSF));
    }
  } else {
    if (tid < 64){
      float c = 0.01f * rsg[0];
      xout[row*Dn+tid] = o + c*(o - basin_seq[row*Dn+tid]);
    }
  }
}

// ---- blocks 0..255: pass-1 layer-0 fbgate + pnorm (4 rows/block); block 256: basin+temps
__global__ __launch_bounds__(256) void k_basinprep(
    const float* __restrict__ st3, const float* __restrict__ st0,
    const float* __restrict__ W_fb, const float* __restrict__ b_fb,
    float* __restrict__ xA, float* __restrict__ sA,
    const float* __restrict__ Wc1, const float* __restrict__ bc1,
    const float* __restrict__ Wc2, const float* __restrict__ bc2,
    const float* __restrict__ Wu,  const float* __restrict__ bu,
    const float* __restrict__ cb_in, float* __restrict__ cb_out,
    const float* __restrict__ W_temp, const float* __restrict__ b_temp,
    float* __restrict__ temps){
  int tid = threadIdx.x, wid = tid>>6, lane = tid&63;
  __shared__ __align__(16) float comb4[4][128];
  __shared__ float pooled[128];
  __shared__ float h1[64];
  __shared__ float hb[128];
  __shared__ float combb[128];
  if (blockIdx.x < 256){
    int row = blockIdx.x*4 + wid;
    float xv = st3[row*Dn+lane];
    float pv = st0[row*Dn+lane];
    comb4[wid][lane] = xv; comb4[wid][64+lane] = pv;
    __syncthreads();
    const float4* W  = (const float4*)(W_fb + (size_t)lane*2*Dn);   // l = 0
    const float4* c4 = (const float4*)comb4[wid];
    float g0=0.f,g1=0.f;
    #pragma unroll
    for (int k=0;k<32;k+=2){
      float4 w0=W[k],   c0=c4[k];
      float4 w1=W[k+1], c1=c4[k+1];
      g0 += w0.x*c0.x + w0.y*c0.y + w0.z*c0.z + w0.w*c0.w;
      g1 += w1.x*c1.x + w1.y*c1.y + w1.z*c1.z + w1.w*c1.w;
    }
    float g = sigmoidf_(g0+g1 + b_fb[lane]);
    float xg = xv*g + pv*(1.0f-g);
    xA[row*Dn+lane] = xg;
    float s = softplusf_(xg);
    float sum = waveReduceSum(s);
    float p = fmaxf(s/(sum+EPSF), EPSF);
    float sum2 = waveReduceSum(p);
    sA[row*Dn+lane] = sqrtf(p/(sum2+EPSF));
  } else {
    // basin: pool + compress MLP + basin update + pass-1 temperatures
    if (tid < 128){
      int b = tid >> 6, d = tid & 63;
      float acc=0.f;
      const float* xb = st3 + (size_t)b*Tn*Dn + d;
      for (int t=0;t<Tn;t++) acc += xb[t*Dn];
      pooled[tid] = acc * (1.0f/Tn);
    }
    __syncthreads();
    if (tid < 64){
      int b = tid >> 5, h = tid & 31;
      float acc=0.f;
      #pragma unroll 8
      for (int d2=0; d2<Dn; d2++) acc += pooled[b*64+d2]*Wc1[h*Dn+d2];
      h1[tid] = tanhf(acc + bc1[h]);
    }
    __syncthreads();
    if (tid < 128){
      int b = tid >> 6, d = tid & 63;
      float acc=0.f;
      #pragma unroll 8
      for (int h2=0; h2<32; h2++) acc += h1[b*32+h2]*Wc2[d*32+h2];
      hb[tid] = tanhf(acc + bc2[d]);
    }
    __syncthreads();
    if (tid < 64){
      float agg = 0.5f*(hb[tid] + hb[64+tid]);
      combb[tid] = cb_in[tid];
      combb[64+tid] = agg;
    }
    __syncthreads();
    if (tid < 64){
      float acc=0.f;
      #pragma unroll 8
      for (int k=0;k<128;k++) acc += Wu[tid*128+k]*combb[k];
      float g = sigmoidf_(acc + bu[tid]);
      float nb = combb[tid]*(1.0f-g) + combb[64+tid]*g;
      cb_out[tid] = nb;
      #pragma unroll
      for (int l=0;l<Ln;l++){
        float v = waveReduceSum(W_temp[l*Dn + tid]*nb);
        if (tid==0) temps[l] = sigmoidf_(v + b_temp[l]) + 0.5f;
      }
    }
  }
}

extern "C" void kernel_launch(void* const* d_in, const int* in_sizes, int n_in,
                              void* d_out, int out_size, void* d_ws, size_t ws_size,
                              hipStream_t stream) {
  const float* basin_seq    = (const float*)d_in[0];
  const float* basin_coords = (const float*)d_in[1];
  const float* W_temp       = (const float*)d_in[2];
  const float* b_temp       = (const float*)d_in[3];
  const float* res_scale    = (const float*)d_in[4];
  const float* W_fb         = (const float*)d_in[5];
  const float* b_fb         = (const float*)d_in[6];
  const float* Wc1          = (const float*)d_in[7];
  const float* bc1          = (const float*)d_in[8];
  const float* Wc2          = (const float*)d_in[9];
  const float* bc2          = (const float*)d_in[10];
  const float* Wu           = (const float*)d_in[11];
  const float* bu           = (const float*)d_in[12];
  const float* rsg          = (const float*)d_in[13];
  float* out = (float*)d_out;
  float* ws  = (float*)d_ws;

  const size_t N = NELEM; // 65536
  float* sA    = ws;
  float* sB    = ws + N;
  float* xA    = ws + 2*N;
  float* xB    = ws + 3*N;
  float* st    = ws + 4*N;        // 4 layer states (pass 0)
  float* temps = ws + 8*N;        // 4 floats
  float* cb    = ws + 8*N + 64;   // 64 floats
  float* st0 = st, *st1 = st+N, *st2 = st+2*N, *st3 = st+3*N;

  // ---- pass 0
  k_prologue<<<257,256,0,stream>>>(basin_seq, sA, W_temp, b_temp, basin_coords, temps);
  k_attn<0><<<ROWS,512,0,stream>>>(basin_seq, sA, temps, res_scale, 0, st0, sB,
                                   nullptr,nullptr,nullptr,nullptr,nullptr);
  k_attn<0><<<ROWS,512,0,stream>>>(st0, sB, temps, res_scale, 1, st1, sA,
                                   nullptr,nullptr,nullptr,nullptr,nullptr);
  k_attn<0><<<ROWS,512,0,stream>>>(st1, sA, temps, res_scale, 2, st2, sB,
                                   nullptr,nullptr,nullptr,nullptr,nullptr);
  k_attn<1><<<ROWS,512,0,stream>>>(st2, sB, temps, res_scale, 3, st3, nullptr,
                                   nullptr,nullptr,nullptr,nullptr,nullptr);
  // ---- basin update + pass-1 layer-0 prep
  k_basinprep<<<257,256,0,stream>>>(st3, st0, W_fb, b_fb, xA, sA,
                                    Wc1, bc1, Wc2, bc2, Wu, bu,
                                    basin_coords, cb, W_temp, b_temp, temps);
  // ---- pass 1
  k_attn<2><<<ROWS,512,0,stream>>>(xA, sA, temps, res_scale, 0, xB, sB,
                                   W_fb + 1*Dn*2*Dn, b_fb + 1*Dn, st1, nullptr,nullptr);
  k_attn<2><<<ROWS,512,0,stream>>>(xB, sB, temps, res_scale, 1, xA, sA,
                                   W_fb + 2*Dn*2*Dn, b_fb + 2*Dn, st2, nullptr,nullptr);
  k_attn<2><<<ROWS,512,0,stream>>>(xA, sA, temps, res_scale, 2, xB, sB,
                                   W_fb + 3*Dn*2*Dn, b_fb + 3*Dn, st3, nullptr,nullptr);
  k_attn<3><<<ROWS,512,0,stream>>>(xB, sB, temps, res_scale, 3, out, nullptr,
                                   nullptr,nullptr,nullptr, basin_seq, rsg);
}

// Round 4
// 215.186 us; speedup vs baseline: 1.6213x; 1.6213x over previous
//
#include <hip/hip_runtime.h>
#include <math.h>

#define EPSF 1e-8f
#define Bn 2
#define Tn 512
#define Dn 64
#define Ln 4
#define ROWS (Bn*Tn)
#define NELEM (Bn*Tn*Dn)

__device__ __forceinline__ float sigmoidf_(float x){ return 1.0f/(1.0f+expf(-x)); }
__device__ __forceinline__ float softplusf_(float x){ return fmaxf(x,0.0f) + log1pf(expf(-fabsf(x))); }

__device__ __forceinline__ float waveReduceSum(float v){
  #pragma unroll
  for (int off=1; off<64; off<<=1) v += __shfl_xor(v, off, 64);
  return v;
}
__device__ __forceinline__ float waveReduceMax(float v){
  #pragma unroll
  for (int off=1; off<64; off<<=1) v = fmaxf(v, __shfl_xor(v, off, 64));
  return v;
}

// ---- prologue: pnorm(basin_seq) -> sA (blocks 0..255, 4 rows each) ; temps (block 256)
__global__ __launch_bounds__(256) void k_prologue(
    const float* __restrict__ basin_seq, float* __restrict__ sA,
    const float* __restrict__ W_temp, const float* __restrict__ b_temp,
    const float* __restrict__ cb0, float* __restrict__ temps){
  int tid = threadIdx.x, wid = tid>>6, lane = tid&63;
  if (blockIdx.x < 256){
    int row = blockIdx.x*4 + wid;
    float s = softplusf_(basin_seq[row*Dn+lane]);
    float sum = waveReduceSum(s);
    float p = fmaxf(s/(sum+EPSF), EPSF);
    float sum2 = waveReduceSum(p);
    sA[row*Dn+lane] = sqrtf(p/(sum2+EPSF));
  } else if (tid < 64){
    float cbv = cb0[tid];
    #pragma unroll
    for (int l=0;l<Ln;l++){
      float v = waveReduceSum(W_temp[l*Dn + tid]*cbv);
      if (tid==0) temps[l] = sigmoidf_(v + b_temp[l]) + 0.5f;
    }
  }
}

// ---- QFI attention, NI=4 rows per block, 1024 threads, grid 256 (1 block/CU).
// MODE 0: pass0 l<3  : write xout(=st[l]) + pnorm -> sbuf_out
// MODE 1: pass0 l==3 : write xout(=st[3])
// MODE 2: pass1 l<3  : fbgate(l+1) + write xout + pnorm -> sbuf_out
// MODE 3: pass1 l==3 : final residual -> xout(=out)
template<int MODE>
__global__ __launch_bounds__(1024, 4) void k_attn(
    const float* __restrict__ xin, const float* __restrict__ sbuf,
    const float* __restrict__ temps, const float* __restrict__ res_scale, int l,
    float* __restrict__ xout, float* __restrict__ sbuf_out,
    const float* __restrict__ Wfb_next, const float* __restrict__ bfb_next,
    const float* __restrict__ prev_next,
    const float* __restrict__ basin_seq, const float* __restrict__ rsg){
  __shared__ __align__(16) union {
    float st[64*260];      // transposed s tile [k][j], row pad 260
    float part[16*4*256];  // [h][i][j]
    float red[16*4*64];    // [w][i][d]
  } u;
  __shared__ __align__(16) float lg[4*512];
  __shared__ __align__(16) float PT[512*4];
  __shared__ __align__(16) float s_i4t[64*4];  // [k][i]
  __shared__ float redw[32];
  __shared__ __align__(16) float comb[4*128];
  __shared__ __align__(16) float gred[64*4];   // [d][i]

  int row0 = blockIdx.x*4;
  int b = row0 >> 9;
  int tid = threadIdx.x;
  int wav = tid>>6, lane = tid&63;
  const float* sb = sbuf + (size_t)b*Tn*Dn;
  const float* xb = xin + (size_t)b*Tn*Dn;
  float invT = 1.0f / fmaxf(temps[l], 1e-6f);

  if (tid < 256){ int i = tid>>6, k = tid&63; s_i4t[k*4+i] = sbuf[(size_t)(row0+i)*Dn + k]; }
  __syncthreads();

  // ---- phase A: logits, two j-tiles of 256
  for (int t=0; t<2; ++t){
    // stage transposed s tile (coalesced global reads)
    {
      int j_l = tid>>4;            // 0..63
      int k0 = (tid&15)*4;
      #pragma unroll
      for (int pass=0; pass<4; ++pass){
        int j = pass*64 + j_l;
        float4 v = *(const float4*)(sb + (size_t)(t*256 + j)*Dn + k0);
        u.st[(k0+0)*260 + j] = v.x;
        u.st[(k0+1)*260 + j] = v.y;
        u.st[(k0+2)*260 + j] = v.z;
        u.st[(k0+3)*260 + j] = v.w;
      }
    }
    __syncthreads();
    // dots: wave wav owns k-slice [wav*4, wav*4+4); lane g owns 4 j's
    float4 a0 = {0,0,0,0}, a1 = a0, a2 = a0, a3 = a0;  // [i][c]
    {
      int g = lane;
      #pragma unroll
      for (int kk=0; kk<4; ++kk){
        int k = wav*4 + kk;
        float4 vi = *(const float4*)&s_i4t[k*4];
        float4 vj = *(const float4*)&u.st[k*260 + g*4];
        a0.x += vi.x*vj.x; a0.y += vi.x*vj.y; a0.z += vi.x*vj.z; a0.w += vi.x*vj.w;
        a1.x += vi.y*vj.x; a1.y += vi.y*vj.y; a1.z += vi.y*vj.z; a1.w += vi.y*vj.w;
        a2.x += vi.z*vj.x; a2.y += vi.z*vj.y; a2.z += vi.z*vj.z; a2.w += vi.z*vj.w;
        a3.x += vi.w*vj.x; a3.y += vi.w*vj.y; a3.z += vi.w*vj.z; a3.w += vi.w*vj.w;
      }
    }
    __syncthreads();   // s_t reads done; part may overwrite
    *(float4*)&u.part[(wav*4+0)*256 + lane*4] = a0;
    *(float4*)&u.part[(wav*4+1)*256 + lane*4] = a1;
    *(float4*)&u.part[(wav*4+2)*256 + lane*4] = a2;
    *(float4*)&u.part[(wav*4+3)*256 + lane*4] = a3;
    __syncthreads();
    // combine 16 k-slices -> logit
    {
      int i = tid>>8, j = tid&255;
      float s = 0.f;
      #pragma unroll
      for (int h=0;h<16;h++) s += u.part[(h*4+i)*256 + j];
      s = fminf(fmaxf(s, -1.0f+1e-6f), 1.0f-1e-6f);
      lg[i*512 + t*256 + j] = -2.0f*acosf(s)*invT;
    }
    __syncthreads();
  }

  // ---- softmax over 512 per row (wave w has i = w>>2 uniform)
  {
    int i = tid>>8, j = tid&255;
    float av = lg[i*512 + j], bv = lg[i*512 + 256 + j];
    float wm = waveReduceMax(fmaxf(av,bv));
    if (lane==0) redw[wav] = wm;
  }
  __syncthreads();
  {
    int i = tid>>8, j = tid&255;
    float mv = fmaxf(fmaxf(redw[i*4],redw[i*4+1]),fmaxf(redw[i*4+2],redw[i*4+3]));
    float e0 = expf(lg[i*512 + j] - mv);
    float e1 = expf(lg[i*512 + 256 + j] - mv);
    PT[j*4+i] = e0; PT[(256+j)*4+i] = e1;
    float s_ = waveReduceSum(e0+e1);
    if (lane==0) redw[16+wav] = s_;
  }
  __syncthreads();

  // ---- PV: thread (d4 = (tid&15)*4, jg = tid>>4), 8 j's each
  {
    float4 o0={0,0,0,0},o1=o0,o2=o0,o3=o0;   // [i][c]
    int d4 = (tid&15)*4, jg = tid>>4;
    #pragma unroll
    for (int jj=0;jj<8;jj++){
      int j = jg*8+jj;
      float4 pt = *(const float4*)&PT[j*4];
      float4 xv = *(const float4*)(xb + (size_t)j*Dn + d4);
      o0.x += pt.x*xv.x; o0.y += pt.x*xv.y; o0.z += pt.x*xv.z; o0.w += pt.x*xv.w;
      o1.x += pt.y*xv.x; o1.y += pt.y*xv.y; o1.z += pt.y*xv.z; o1.w += pt.y*xv.w;
      o2.x += pt.z*xv.x; o2.y += pt.z*xv.y; o2.z += pt.z*xv.z; o2.w += pt.z*xv.w;
      o3.x += pt.w*xv.x; o3.y += pt.w*xv.y; o3.z += pt.w*xv.z; o3.w += pt.w*xv.w;
    }
    #pragma unroll
    for (int off=16; off<64; off<<=1){
      o0.x += __shfl_xor(o0.x,off,64); o0.y += __shfl_xor(o0.y,off,64);
      o0.z += __shfl_xor(o0.z,off,64); o0.w += __shfl_xor(o0.w,off,64);
      o1.x += __shfl_xor(o1.x,off,64); o1.y += __shfl_xor(o1.y,off,64);
      o1.z += __shfl_xor(o1.z,off,64); o1.w += __shfl_xor(o1.w,off,64);
      o2.x += __shfl_xor(o2.x,off,64); o2.y += __shfl_xor(o2.y,off,64);
      o2.z += __shfl_xor(o2.z,off,64); o2.w += __shfl_xor(o2.w,off,64);
      o3.x += __shfl_xor(o3.x,off,64); o3.y += __shfl_xor(o3.y,off,64);
      o3.z += __shfl_xor(o3.z,off,64); o3.w += __shfl_xor(o3.w,off,64);
    }
    __syncthreads();    // part reads long done; red may overwrite
    if (lane < 16){
      int dd4 = lane*4;
      *(float4*)&u.red[(wav*4+0)*64 + dd4] = o0;
      *(float4*)&u.red[(wav*4+1)*64 + dd4] = o1;
      *(float4*)&u.red[(wav*4+2)*64 + dd4] = o2;
      *(float4*)&u.red[(wav*4+3)*64 + dd4] = o3;
    }
  }
  __syncthreads();

  // ---- epilogue: threads < 256 own (i = tid>>6, d = tid&63); wave == row
  int i_ = tid>>6, d_ = tid&63;
  float o = 0.f;
  if (tid < 256){
    float ssum = 0.f;
    #pragma unroll
    for (int w2=0; w2<16; w2++) ssum += u.red[(w2*4+i_)*64 + d_];
    float isum = 1.0f/(redw[16+i_*4]+redw[16+i_*4+1]+redw[16+i_*4+2]+redw[16+i_*4+3]);
    float attn = ssum * isum;
    float xi = xin[(size_t)(row0+i_)*Dn + d_];
    float rs = res_scale[l];
    o = xi + rs*(attn - xi);
  }

  if constexpr (MODE == 0){
    if (tid < 256){
      xout[(size_t)(row0+i_)*Dn + d_] = o;
      float s = softplusf_(o);
      float sum = waveReduceSum(s);
      float p = fmaxf(s/(sum+EPSF), EPSF);
      float sum2 = waveReduceSum(p);
      sbuf_out[(size_t)(row0+i_)*Dn + d_] = sqrtf(p/(sum2+EPSF));
    }
  } else if constexpr (MODE == 1){
    if (tid < 256) xout[(size_t)(row0+i_)*Dn + d_] = o;
  } else if constexpr (MODE == 2){
    if (tid < 256){
      comb[i_*128 + d_] = o;
      comb[i_*128 + 64 + d_] = prev_next[(size_t)(row0+i_)*Dn + d_];
    }
    __syncthreads();
    // gate dot: thread (dd = tid>>4, k16 = tid&15) — coalesced W_fb reads
    {
      int dd = tid>>4, k16 = tid&15;
      const float4* wp = (const float4*)(Wfb_next + (size_t)dd*128 + k16*8);
      float4 w0 = wp[0], w1 = wp[1];
      float ga[4];
      #pragma unroll
      for (int i=0;i<4;i++){
        float4 c0 = *(const float4*)&comb[i*128 + k16*8];
        float4 c1 = *(const float4*)&comb[i*128 + k16*8 + 4];
        ga[i] = w0.x*c0.x + w0.y*c0.y + w0.z*c0.z + w0.w*c0.w
              + w1.x*c1.x + w1.y*c1.y + w1.z*c1.z + w1.w*c1.w;
      }
      #pragma unroll
      for (int off=1; off<16; off<<=1){
        ga[0] += __shfl_xor(ga[0],off,64);
        ga[1] += __shfl_xor(ga[1],off,64);
        ga[2] += __shfl_xor(ga[2],off,64);
        ga[3] += __shfl_xor(ga[3],off,64);
      }
      if ((lane&15)==0){
        float4 gv = {ga[0], ga[1], ga[2], ga[3]};
        *(float4*)&gred[dd*4] = gv;
      }
    }
    __syncthreads();
    if (tid < 256){
      float g = sigmoidf_(gred[d_*4 + i_] + bfb_next[d_]);
      float pvv = comb[i_*128 + 64 + d_];
      float xg = o*g + pvv*(1.0f-g);
      xout[(size_t)(row0+i_)*Dn + d_] = xg;
      float s = softplusf_(xg);
      float sum = waveReduceSum(s);
      float p = fmaxf(s/(sum+EPSF), EPSF);
      float sum2 = waveReduceSum(p);
      sbuf_out[(size_t)(row0+i_)*Dn + d_] = sqrtf(p/(sum2+EPSF));
    }
  } else {
    if (tid < 256){
      float c = 0.01f * rsg[0];
      xout[(size_t)(row0+i_)*Dn + d_] = o + c*(o - basin_seq[(size_t)(row0+i_)*Dn + d_]);
    }
  }
}

// ---- blocks 0..255: pass-1 layer-0 fbgate + pnorm (4 rows/block); block 256: basin+temps
__global__ __launch_bounds__(256) void k_basinprep(
    const float* __restrict__ st3, const float* __restrict__ st0,
    const float* __restrict__ W_fb, const float* __restrict__ b_fb,
    float* __restrict__ xA, float* __restrict__ sA,
    const float* __restrict__ Wc1, const float* __restrict__ bc1,
    const float* __restrict__ Wc2, const float* __restrict__ bc2,
    const float* __restrict__ Wu,  const float* __restrict__ bu,
    const float* __restrict__ cb_in, float* __restrict__ cb_out,
    const float* __restrict__ W_temp, const float* __restrict__ b_temp,
    float* __restrict__ temps){
  int tid = threadIdx.x, wid = tid>>6, lane = tid&63;
  __shared__ __align__(16) float comb4[4][128];
  __shared__ float pooled[128];
  __shared__ float h1[64];
  __shared__ float hb[128];
  __shared__ float combb[128];
  if (blockIdx.x < 256){
    int row = blockIdx.x*4 + wid;
    float xv = st3[row*Dn+lane];
    float pv = st0[row*Dn+lane];
    comb4[wid][lane] = xv; comb4[wid][64+lane] = pv;
    __syncthreads();
    const float4* W  = (const float4*)(W_fb + (size_t)lane*2*Dn);   // l = 0
    const float4* c4 = (const float4*)comb4[wid];
    float g0=0.f,g1=0.f;
    #pragma unroll
    for (int k=0;k<32;k+=2){
      float4 w0=W[k],   c0=c4[k];
      float4 w1=W[k+1], c1=c4[k+1];
      g0 += w0.x*c0.x + w0.y*c0.y + w0.z*c0.z + w0.w*c0.w;
      g1 += w1.x*c1.x + w1.y*c1.y + w1.z*c1.z + w1.w*c1.w;
    }
    float g = sigmoidf_(g0+g1 + b_fb[lane]);
    float xg = xv*g + pv*(1.0f-g);
    xA[row*Dn+lane] = xg;
    float s = softplusf_(xg);
    float sum = waveReduceSum(s);
    float p = fmaxf(s/(sum+EPSF), EPSF);
    float sum2 = waveReduceSum(p);
    sA[row*Dn+lane] = sqrtf(p/(sum2+EPSF));
  } else {
    if (tid < 128){
      int b = tid >> 6, d = tid & 63;
      float acc=0.f;
      const float* xb = st3 + (size_t)b*Tn*Dn + d;
      for (int t=0;t<Tn;t++) acc += xb[t*Dn];
      pooled[tid] = acc * (1.0f/Tn);
    }
    __syncthreads();
    if (tid < 64){
      int b = tid >> 5, h = tid & 31;
      float acc=0.f;
      #pragma unroll 8
      for (int d2=0; d2<Dn; d2++) acc += pooled[b*64+d2]*Wc1[h*Dn+d2];
      h1[tid] = tanhf(acc + bc1[h]);
    }
    __syncthreads();
    if (tid < 128){
      int b = tid >> 6, d = tid & 63;
      float acc=0.f;
      #pragma unroll 8
      for (int h2=0; h2<32; h2++) acc += h1[b*32+h2]*Wc2[d*32+h2];
      hb[tid] = tanhf(acc + bc2[d]);
    }
    __syncthreads();
    if (tid < 64){
      float agg = 0.5f*(hb[tid] + hb[64+tid]);
      combb[tid] = cb_in[tid];
      combb[64+tid] = agg;
    }
    __syncthreads();
    if (tid < 64){
      float acc=0.f;
      #pragma unroll 8
      for (int k=0;k<128;k++) acc += Wu[tid*128+k]*combb[k];
      float g = sigmoidf_(acc + bu[tid]);
      float nb = combb[tid]*(1.0f-g) + combb[64+tid]*g;
      cb_out[tid] = nb;
      #pragma unroll
      for (int l=0;l<Ln;l++){
        float v = waveReduceSum(W_temp[l*Dn + tid]*nb);
        if (tid==0) temps[l] = sigmoidf_(v + b_temp[l]) + 0.5f;
      }
    }
  }
}

extern "C" void kernel_launch(void* const* d_in, const int* in_sizes, int n_in,
                              void* d_out, int out_size, void* d_ws, size_t ws_size,
                              hipStream_t stream) {
  const float* basin_seq    = (const float*)d_in[0];
  const float* basin_coords = (const float*)d_in[1];
  const float* W_temp       = (const float*)d_in[2];
  const float* b_temp       = (const float*)d_in[3];
  const float* res_scale    = (const float*)d_in[4];
  const float* W_fb         = (const float*)d_in[5];
  const float* b_fb         = (const float*)d_in[6];
  const float* Wc1          = (const float*)d_in[7];
  const float* bc1          = (const float*)d_in[8];
  const float* Wc2          = (const float*)d_in[9];
  const float* bc2          = (const float*)d_in[10];
  const float* Wu           = (const float*)d_in[11];
  const float* bu           = (const float*)d_in[12];
  const float* rsg          = (const float*)d_in[13];
  float* out = (float*)d_out;
  float* ws  = (float*)d_ws;

  const size_t N = NELEM; // 65536
  float* sA    = ws;
  float* sB    = ws + N;
  float* xA    = ws + 2*N;
  float* xB    = ws + 3*N;
  float* st    = ws + 4*N;        // 4 layer states (pass 0)
  float* temps = ws + 8*N;        // 4 floats
  float* cb    = ws + 8*N + 64;   // 64 floats
  float* st0 = st, *st1 = st+N, *st2 = st+2*N, *st3 = st+3*N;

  const int GA = ROWS/4;  // 256 blocks

  // ---- pass 0
  k_prologue<<<257,256,0,stream>>>(basin_seq, sA, W_temp, b_temp, basin_coords, temps);
  k_attn<0><<<GA,1024,0,stream>>>(basin_seq, sA, temps, res_scale, 0, st0, sB,
                                  nullptr,nullptr,nullptr,nullptr,nullptr);
  k_attn<0><<<GA,1024,0,stream>>>(st0, sB, temps, res_scale, 1, st1, sA,
                                  nullptr,nullptr,nullptr,nullptr,nullptr);
  k_attn<0><<<GA,1024,0,stream>>>(st1, sA, temps, res_scale, 2, st2, sB,
                                  nullptr,nullptr,nullptr,nullptr,nullptr);
  k_attn<1><<<GA,1024,0,stream>>>(st2, sB, temps, res_scale, 3, st3, nullptr,
                                  nullptr,nullptr,nullptr,nullptr,nullptr);
  // ---- basin update + pass-1 layer-0 prep
  k_basinprep<<<257,256,0,stream>>>(st3, st0, W_fb, b_fb, xA, sA,
                                    Wc1, bc1, Wc2, bc2, Wu, bu,
                                    basin_coords, cb, W_temp, b_temp, temps);
  // ---- pass 1
  k_attn<2><<<GA,1024,0,stream>>>(xA, sA, temps, res_scale, 0, xB, sB,
                                  W_fb + 1*Dn*2*Dn, b_fb + 1*Dn, st1, nullptr,nullptr);
  k_attn<2><<<GA,1024,0,stream>>>(xB, sB, temps, res_scale, 1, xA, sA,
                                  W_fb + 2*Dn*2*Dn, b_fb + 2*Dn, st2, nullptr,nullptr);
  k_attn<2><<<GA,1024,0,stream>>>(xA, sA, temps, res_scale, 2, xB, sB,
                                  W_fb + 3*Dn*2*Dn, b_fb + 3*Dn, st3, nullptr,nullptr);
  k_attn<3><<<GA,1024,0,stream>>>(xB, sB, temps, res_scale, 3, out, nullptr,
                                  nullptr,nullptr,nullptr, basin_seq, rsg);
}